// Round 16
// baseline (216.575 us; speedup 1.0000x reference)
//
#include <hip/hip_runtime.h>
#include <hip/hip_bf16.h>
#include <stdint.h>

// Transformer-XL attention prob: T=1024 B=4 D=1024 NH=8 DH=128 MEM=1024 TM=2048
typedef __bf16 bf16;
typedef __bf16 bf16x4 __attribute__((ext_vector_type(4)));
typedef __bf16 bf16x8 __attribute__((ext_vector_type(8)));
typedef float f32x4 __attribute__((ext_vector_type(4)));

__device__ __forceinline__ void gload_lds16(const void* g, void* l) {
  __builtin_amdgcn_global_load_lds((const __attribute__((address_space(1))) void*)g,
                                   (__attribute__((address_space(3))) void*)l, 16, 0, 0);
}

// ---------------- fused pre: ln (blocks 0..8191) + prep (8192..28671) + setup (28672) --
__global__ __launch_bounds__(256) void pre_kernel(const float* __restrict__ h, const float* __restrict__ mm,
                                                  const float* __restrict__ sc, const float* __restrict__ bi,
                                                  bf16* __restrict__ catln, const float* __restrict__ qw,
                                                  const float* __restrict__ kw, const float* __restrict__ rw,
                                                  bf16* __restrict__ qwb, bf16* __restrict__ kwb,
                                                  bf16* __restrict__ rwb, bf16* __restrict__ pe,
                                                  const void* __restrict__ rst, const void* __restrict__ orst,
                                                  int* __restrict__ jmin) {
  int bx = blockIdx.x;
  int tid = threadIdx.x;
  if (bx < 8192) {
    // ---- LayerNorm of concat(m,h) -> bf16 [TM*B][1024] ----
    int row = bx;
    const float* src = (row < 4096) ? (mm + (size_t)row * 1024) : (h + (size_t)(row - 4096) * 1024);
    float4 v = ((const float4*)src)[tid];
    float s1 = v.x + v.y + v.z + v.w;
    float s2 = v.x * v.x + v.y * v.y + v.z * v.z + v.w * v.w;
    int lane = tid & 63, w = tid >> 6;
    for (int o = 32; o; o >>= 1) { s1 += __shfl_down(s1, o); s2 += __shfl_down(s2, o); }
    __shared__ float red[8];
    if (lane == 0) { red[w] = s1; red[w + 4] = s2; }
    __syncthreads();
    float S1 = red[0] + red[1] + red[2] + red[3];
    float S2 = red[4] + red[5] + red[6] + red[7];
    float mean = S1 * (1.0f / 1024.0f);
    float var = S2 * (1.0f / 1024.0f) - mean * mean;
    float rstd = rsqrtf(var + 1e-5f);
    bf16x4 o;
#pragma unroll
    for (int c = 0; c < 4; ++c) {
      float x = (c == 0) ? v.x : (c == 1) ? v.y : (c == 2) ? v.z : v.w;
      o[c] = (bf16)((x - mean) * rstd * sc[tid * 4 + c] + bi[tid * 4 + c]);
    }
    *(bf16x4*)(catln + (size_t)row * 1024 + tid * 4) = o;
  } else if (bx < 28672) {
    // ---- weights->bf16 + positional encoding ----
    size_t id = (size_t)(bx - 8192) * 256 + tid;
    if (id < 3145728) {
      const float* s = id < 1048576 ? qw : (id < 2097152 ? kw : rw);
      bf16* d = id < 1048576 ? qwb : (id < 2097152 ? kwb : rwb);
      size_t o = id & 1048575;
      d[o] = (bf16)s[o];
    } else {
      size_t p = id - 3145728;                 // < 2097152
      int jj = (int)(p >> 10), dcol = (int)(p & 1023);
      float pos = (float)(2047 - jj);
      int fi = dcol < 512 ? dcol : dcol - 512;
      float f = exp2f(-0.01953125f * (float)fi);   // 1024^(-fi/512)
      float rev = pos * f;                          // revolutions
      rev -= floorf(rev);
      float ang = 6.283185307179586f * rev;
      pe[p] = (bf16)(dcol < 512 ? __sinf(ang) : __cosf(ang));
    }
  } else {
    // ---- setup: detect reset dtype, compute j_min per (i,b) ----
    __shared__ int sflag;
    if (tid == 0) sflag = 0;
    __syncthreads();
    int local = 0;
    for (int idx = tid; idx < 1024; idx += 256) {
      unsigned v1 = ((const unsigned*)rst)[idx];
      unsigned v2 = ((const unsigned*)orst)[idx];
      unsigned vv[2] = {v1, v2};
      for (int t = 0; t < 2; ++t) {
        unsigned v = vv[t];
        if (v == 0x3F800000u) local |= 1;
        else if (v > 1u) local |= 2;
      }
    }
    if (local) atomicOr(&sflag, local);
    __syncthreads();
    int mode = (sflag & 2) ? 2 : ((sflag & 1) ? 1 : 0);
    int lane = tid & 63, w = tid >> 6;
    if (w < 4) {
      int b = w;
      int rv[32];
      int lmax = -1;
#pragma unroll
      for (int u = 0; u < 32; ++u) {
        int s = lane * 32 + u;
        int idx = (s < 1024) ? s * 4 + b : (s - 1024) * 4 + b;
        const void* p = (s < 1024) ? orst : rst;
        int x;
        if (mode == 2)      x = ((const unsigned char*)p)[idx] != 0;
        else if (mode == 1) x = ((const float*)p)[idx] != 0.0f;
        else                x = ((const int*)p)[idx] != 0;
        rv[u] = x;
        if (x) lmax = s;
      }
      int inc = lmax;
      for (int o = 1; o < 64; o <<= 1) {
        int oth = __shfl_up(inc, o);
        if (lane >= o && oth > inc) inc = oth;
      }
      int cur = __shfl_up(inc, 1);
      if (lane == 0) cur = -1;
#pragma unroll
      for (int u = 0; u < 32; ++u) {
        int s = lane * 32 + u;
        if (rv[u]) cur = s;
        if (s >= 1024) jmin[(s - 1024) * 4 + b] = (cur > 0) ? cur : 0;
      }
    }
  }
}

// ---------------- fused GEMM: C = A(MxK) * W(NxK)^T, K=N=1024 -------------------------
// XCD-aware 1D grid: XCD k owns row-panels [14k,14k+14) x all 8 cols -> A panel (3.5MB)
// is L2-resident per XCD instead of streaming all of A (30MB) through every XCD's L2.
__device__ __forceinline__ size_t out_index(int mode, int row, int col) {
  int n = col >> 7, dh = col & 127;
  if (mode <= 0) { int i = row >> 2, b = row & 3; return ((size_t)(b * 8 + n) * 1024 + i) * 128 + dh; }
  if (mode == 1) { int s = row >> 2, b = row & 3; return ((size_t)(b * 8 + n) * 2048 + s) * 128 + dh; }
  return ((size_t)n * 2048 + row) * 128 + dh;
}

__global__ __launch_bounds__(256) void gemm_all(const bf16* __restrict__ catln, const bf16* __restrict__ pe,
                                                const bf16* __restrict__ qwb, const bf16* __restrict__ kwb,
                                                const bf16* __restrict__ rwb, const float* __restrict__ kbias,
                                                const float* __restrict__ rbias, bf16* __restrict__ qkb,
                                                bf16* __restrict__ qrb, bf16* __restrict__ kkv,
                                                bf16* __restrict__ rrv) {
  __shared__ alignas(16) char lA[8192];
  __shared__ alignas(16) char lB[8192];
  const int K = 1024;
  int d = blockIdx.x;                 // 0..895; XCD = d & 7 (round-robin dispatch)
  int kx = d & 7, t = d >> 3;         // t 0..111
  int by = kx * 14 + (t % 14);        // row-panel: XCD kx owns y in [14kx, 14kx+14)
  int bcol = (t / 14) << 7;           // column 0..7
  const bf16* A; const bf16* W; int mode; int brow;
  if (by < 32)      { mode = 0; A = catln + (size_t)4096 * 1024; W = qwb; brow = by << 7; }
  else if (by < 96) { mode = 1; A = catln;                        W = kwb; brow = (by - 32) << 7; }
  else              { mode = 2; A = pe;                           W = rwb; brow = (by - 96) << 7; }
  int tid = threadIdx.x;
  int lane = tid & 63, w = tid >> 6;
  int wr = w >> 1, wc = w & 1;
  f32x4 acc[4][4] = {};
  int r0 = tid >> 2;
  int c8 = (tid & 3) << 3;
  const bf16* gA0 = A + (size_t)(brow + r0) * K + c8;
  const bf16* gB0 = W + (size_t)(bcol + r0) * K + c8;
  char* lAw = lA + w * 1024;
  char* lBw = lB + w * 1024;
  for (int k0 = 0; k0 < K; k0 += 32) {
    if (k0) __syncthreads();
    gload_lds16(gA0 + k0, lAw);
    gload_lds16(gA0 + (size_t)64 * K + k0, lAw + 4096);
    gload_lds16(gB0 + k0, lBw);
    gload_lds16(gB0 + (size_t)64 * K + k0, lBw + 4096);
    __syncthreads();
    const char* pa = lA + (((wr << 6) + (lane & 15)) << 6) + ((lane >> 4) << 4);
    const char* pb = lB + (((wc << 6) + (lane & 15)) << 6) + ((lane >> 4) << 4);
    bf16x8 af[4], bfr[4];
#pragma unroll
    for (int x = 0; x < 4; ++x) {
      af[x] = *(const bf16x8*)(pa + (x << 10));
      bfr[x] = *(const bf16x8*)(pb + (x << 10));
    }
#pragma unroll
    for (int mi = 0; mi < 4; ++mi)
#pragma unroll
      for (int ni = 0; ni < 4; ++ni)
        acc[mi][ni] = __builtin_amdgcn_mfma_f32_16x16x32_bf16(af[mi], bfr[ni], acc[mi][ni], 0, 0, 0);
  }
  int rowb = brow + (wr << 6) + ((lane >> 4) << 2);
  int colb = bcol + (wc << 6) + (lane & 15);
#pragma unroll
  for (int mi = 0; mi < 4; ++mi)
#pragma unroll
    for (int ni = 0; ni < 4; ++ni) {
      int col = colb + (ni << 4);
      float bk = 0.0f, br = 0.0f;
      if (mode == 0) { bk = kbias[col]; br = rbias[col]; }
#pragma unroll
      for (int v = 0; v < 4; ++v) {
        int row = rowb + (mi << 4) + v;
        size_t idx = out_index(mode, row, col);
        if (mode == 0) {
          qkb[idx] = (bf16)(acc[mi][ni][v] + bk);
          qrb[idx] = (bf16)(acc[mi][ni][v] + br);
        } else if (mode == 1) {
          kkv[idx] = (bf16)acc[mi][ni][v];
        } else {
          rrv[idx] = (bf16)acc[mi][ni][v];
        }
      }
    }
}

// ---------------- score v7b: v7 structure; P unit-swizzle = (bn>>1)&7 ----------------
__global__ __launch_bounds__(256, 2) void score2_kernel(const bf16* __restrict__ qk, const bf16* __restrict__ qr,
                                                        const bf16* __restrict__ kk, const bf16* __restrict__ rr,
                                                        const int* __restrict__ jmin, bf16* __restrict__ P,
                                                        float* __restrict__ scaleBuf) {
  __shared__ float sl[64 * 128];                  // 32 KB, S1 scores [i][dd^xsw(i)]
  __shared__ alignas(16) bf16 stg[2][64 * 128];   // 2 x 16 KB pair buffers
  __shared__ int jl_s[64];
  int tid = threadIdx.x, lane = tid & 63;
  int w = (tid >> 6) & 3;
  int bid0 = blockIdx.x;
  int bid = ((bid0 & 7) << 7) | (bid0 >> 3);   // XCD grouping (1024 = 8*128, bijective)
  int bn = bid >> 5;
  int it = (bid >> 1) & 15;
  int hh = bid & 1;                             // dd-half: chunks 4hh..4hh+3
  int i0 = it << 6;
  int b = bn >> 3, n = bn & 7;
  int r15 = lane & 15, kc = lane >> 4;
  int il0 = w << 4;
  int g4 = kc << 2;
  const float scale = 0.08838834764831845f;    // 1/sqrt(128)
  int psw = (bn >> 1) & 7;                     // P unit swizzle (matches scatter)

  if (tid < 64) jl_s[tid] = jmin[(i0 + tid) * 4 + b];

  bf16x8 aK[4], aR[4];
  {
    const bf16* qkrow = qk + ((size_t)bn * 1024 + i0 + il0 + r15) * 128 + kc * 8;
    const bf16* qrrow = qr + ((size_t)bn * 1024 + i0 + il0 + r15) * 128 + kc * 8;
#pragma unroll
    for (int ks = 0; ks < 4; ++ks) {
      aK[ks] = *(const bf16x8*)(qkrow + ks * 32);
      aR[ks] = *(const bf16x8*)(qrrow + ks * 32);
    }
  }

  int su1 = tid, su2 = tid + 256;
  int srow1 = su1 >> 4, scol1 = (su1 & 15) ^ (srow1 & 7);
  int srow2 = su2 >> 4, scol2 = (su2 & 15) ^ (srow2 & 7);
  size_t do1 = (size_t)(su1 & ~63) * 16;
  size_t do2 = (size_t)(su2 & ~63) * 16;
  const bf16* rbase = rr + (size_t)n * 2048 * 128;
  const bf16* kbase = kk + (size_t)bn * 2048 * 128;

  auto issue_pair = [&](int pg) {
    if (pg >= 20) return;
    char* bufb = (char*)stg + (size_t)(pg & 1) * 16384;
#pragma unroll
    for (int k = 0; k < 2; ++k) {
      int ti = pg * 2 + k;
      int ci = ti / 10, si = ti - ci * 10;
      int gc = (hh << 2) + ci;
      const bf16* base = (si < 4) ? rbase : kbase;
      int row0 = (si < 4) ? (1023 + (gc << 7) + (si << 5)) : (i0 + (gc << 7) + ((si - 4) << 5));
      char* db = bufb + (size_t)k * 8192;
      gload_lds16(base + (size_t)(row0 + srow1) * 128 + scol1 * 8, db + do1);
      gload_lds16(base + (size_t)(row0 + srow2) * 128 + scol2 * 8, db + do2);
    }
  };

  int xsw = (((il0 >> 2) + kc) & 7) << 4;      // row-group swizzle (uniform over v)
  f32x4 s2r[8];

  issue_pair(0);
  for (int cl = 0; cl < 4; ++cl) {
    int gc = (hh << 2) + cl;
    int c128 = gc << 7;
#pragma unroll
    for (int q = 0; q < 5; ++q) {
      int g = cl * 5 + q;
      __syncthreads();                         // drains vmcnt -> pair g data visible
      issue_pair(g + 1);                       // overwrites pair g-1's buffer (safe)
      const char* pb = (const char*)stg + (size_t)(g & 1) * 16384;
      __builtin_amdgcn_s_setprio(1);
      if (q < 2) {
#pragma unroll
        for (int sc = 0; sc < 4; ++sc) {
          const char* sb = pb + (sc >> 1) * 8192;
          int fr = ((sc & 1) << 4) + r15;
          f32x4 acc = {};
#pragma unroll
          for (int ks = 0; ks < 4; ++ks) {
            int lcol = (ks << 2) + kc;
            bf16x8 bf = *(const bf16x8*)(sb + fr * 256 + ((lcol ^ (fr & 7)) << 4));
            acc = __builtin_amdgcn_mfma_f32_16x16x32_bf16(aR[ks], bf, acc, 0, 0, 0);
          }
          s2r[q * 4 + sc] = acc;
        }
      } else {
#pragma unroll
        for (int sc = 0; sc < 4; ++sc) {
          int jl0 = ((q - 2) << 6) + (sc << 4);
          int doff = jl0 - il0;
          if (doff < -15 || doff > 142) continue;
          const char* sb = pb + (sc >> 1) * 8192;
          int fr = ((sc & 1) << 4) + r15;
          f32x4 acc = {};
#pragma unroll
          for (int ks = 0; ks < 4; ++ks) {
            int lcol = (ks << 2) + kc;
            bf16x8 bf = *(const bf16x8*)(sb + fr * 256 + ((lcol ^ (fr & 7)) << 4));
            acc = __builtin_amdgcn_mfma_f32_16x16x32_bf16(aK[ks], bf, acc, 0, 0, 0);
          }
          int dbase = jl0 + r15 - il0 - g4;   // ddl = jl - il
#pragma unroll
          for (int v = 0; v < 4; ++v) {
            int ddl = dbase - v;
            if ((unsigned)ddl < 128u) {
              sl[(il0 + g4 + v) * 128 + (ddl ^ xsw)] = acc[v];
            }
          }
        }
      }
      __builtin_amdgcn_s_setprio(0);
      if (q == 4) {
#pragma unroll
        for (int v = 0; v < 4; ++v) {
          int il = il0 + g4 + v;
          int ig = i0 + il;
          int jm = jl_s[il];
          int lo = (ig + 1 > jm) ? ig + 1 : jm;
          int ddlo = lo - ig;
          float vals[8];
          float mx = -3.0e38f;
#pragma unroll
          for (int u = 0; u < 8; ++u) {
            int ddc = (u << 4) + r15;              // chunk-local dd
            float x = (s2r[u][v] + sl[il * 128 + (ddc ^ xsw)]) * scale;
            x = fminf(fmaxf(x, -65000.0f), 65000.0f);
            float xm = ((c128 + ddc) >= ddlo) ? x : -3.0e38f;
            vals[u] = xm;
            mx = fmaxf(mx, xm);
          }
          for (int o = 8; o; o >>= 1) mx = fmaxf(mx, __shfl_xor(mx, o));
          float sum = 0.0f;
#pragma unroll
          for (int u = 0; u < 8; ++u) {
            float e = (vals[u] > -1.0e38f) ? __expf(vals[u] - mx) : 0.0f;
            vals[u] = e;
            sum += e;
          }
          for (int o = 8; o; o >>= 1) sum += __shfl_xor(sum, o);
          size_t pbase = ((size_t)bn * 1024 + ig) * 1024;
#pragma unroll
          for (int u = 0; u < 8; ++u) {
            int dd = c128 + (u << 4) + r15;
            P[pbase + (((dd >> 3) ^ psw) << 3) + (dd & 7)] = (bf16)vals[u];
          }
          if (r15 == 0) {
            float2 ms = make_float2(mx, sum);
            *(float2*)(scaleBuf + (((size_t)ig * 32 + bn) * 8 + gc) * 2) = ms;
          }
        }
      }
    }
  }
}

// ---------------- fallback: full-LDS score writing normalized out directly -----------
__global__ __launch_bounds__(256) void score_full(const bf16* __restrict__ qk, const bf16* __restrict__ qr,
                                                  const bf16* __restrict__ kk, const bf16* __restrict__ rr,
                                                  const int* __restrict__ jmin, float* __restrict__ out) {
  __shared__ float sl[16 * 1024];
  int tid = threadIdx.x, lane = tid & 63, w = tid >> 6;
  int bid = blockIdx.x;
  int i0 = (bid & 63) << 4;
  int bn = bid >> 6;
  int b = bn >> 3, n = bn & 7;
  int r15 = lane & 15, kc = lane >> 4;
  bf16x8 aq[4], ar[4];
  {
    const bf16* qkrow = qk + ((size_t)bn * 1024 + i0 + r15) * 128 + kc * 8;
    const bf16* qrrow = qr + ((size_t)bn * 1024 + i0 + r15) * 128 + kc * 8;
#pragma unroll
    for (int f = 0; f < 4; ++f) {
      aq[f] = *(const bf16x8*)(qkrow + f * 32);
      ar[f] = *(const bf16x8*)(qrrow + f * 32);
    }
  }
  for (int t = w; t < 64; t += 4) {
    int dd0 = t << 4;
    const bf16* rrow = rr + ((size_t)n * 2048 + 1023 + dd0 + r15) * 128 + kc * 8;
    f32x4 acc = {};
#pragma unroll
    for (int f = 0; f < 4; ++f)
      acc = __builtin_amdgcn_mfma_f32_16x16x32_bf16(ar[f], *(const bf16x8*)(rrow + f * 32), acc, 0, 0, 0);
    int dd = dd0 + r15;
#pragma unroll
    for (int v = 0; v < 4; ++v) sl[(kc * 4 + v) * 1024 + dd] = acc[v];
  }
  __syncthreads();
  for (int t = w; t < 65; t += 4) {
    int j0 = i0 + (t << 4);
    const bf16* krow = kk + ((size_t)bn * 2048 + j0 + r15) * 128 + kc * 8;
    f32x4 acc = {};
#pragma unroll
    for (int f = 0; f < 4; ++f)
      acc = __builtin_amdgcn_mfma_f32_16x16x32_bf16(aq[f], *(const bf16x8*)(krow + f * 32), acc, 0, 0, 0);
    int jc = (t << 4) + r15;
#pragma unroll
    for (int v = 0; v < 4; ++v) {
      int ii = kc * 4 + v;
      int dd = jc - ii;
      if (dd >= 1 && dd <= 1023) sl[ii * 1024 + dd] += acc[v];
    }
  }
  __syncthreads();
  const float scale = 0.08838834764831845f;
  for (int ii = w; ii < 16; ii += 4) {
    int i = i0 + ii;
    int jm = jmin[i * 4 + b];
    int lo = (i + 1 > jm) ? i + 1 : jm;
    int ddlo = lo - i;
    size_t ob = (size_t)i * 65536 + bn;
    if (ddlo > 1023) {
      for (int j = lane; j < 2048; j += 64) out[ob + (size_t)j * 32] = 0.0f;
      continue;
    }
    float vals[16];
    float mx = -3.0e38f;
#pragma unroll
    for (int c = 0; c < 16; ++c) {
      int dd = (c << 6) + lane;
      float x = sl[ii * 1024 + dd] * scale;
      x = fminf(fmaxf(x, -65000.0f), 65000.0f);
      float xm = (dd >= ddlo) ? x : -3.0e38f;
      vals[c] = xm;
      mx = fmaxf(mx, xm);
    }
    for (int o = 32; o; o >>= 1) mx = fmaxf(mx, __shfl_xor(mx, o));
    float sum = 0.0f;
#pragma unroll
    for (int c = 0; c < 16; ++c) {
      float e = (vals[c] > -1.0e38f) ? __expf(vals[c] - mx) : 0.0f;
      vals[c] = e;
      sum += e;
    }
    for (int o = 32; o; o >>= 1) sum += __shfl_xor(sum, o);
    float inv = 1.0f / sum;
    for (int j = lane; j < 2048; j += 64) {
      int dd = j - i;
      float pv = 0.0f;
      if (dd >= ddlo && dd <= 1023) {
        float x = sl[ii * 1024 + dd] * scale;
        x = fminf(fmaxf(x, -65000.0f), 65000.0f);
        pv = __expf(x - mx) * inv;
      }
      out[ob + (size_t)j * 32] = pv;
    }
  }
}

// ---------------- scatter v3: zero-writes overlap the P->LDS staging -----------------
__global__ __launch_bounds__(256) void scatter_kernel(const bf16* __restrict__ P,
                                                      const float* __restrict__ scaleBuf,
                                                      float* __restrict__ out) {
  __shared__ alignas(16) bf16 ld[32 * 1024];  // 64 KB
  __shared__ float sc_l[32 * 8];
  int i = blockIdx.x;
  int tid = threadIdx.x;
#pragma unroll
  for (int it = 0; it < 16; ++it) {
    int c = it * 256 + tid;                 // 16B-units; bn uniform per wave
    int bn = c >> 7, u = c & 127;
    const bf16* src = P + ((size_t)bn * 1024 + i) * 1024 + u * 8;
    gload_lds16(src, (char*)ld + (size_t)(it * 256 + (tid & ~63)) * 16);
  }
  {
    int bn_t = tid >> 3, c_t = tid & 7;
    const float2* sp = (const float2*)(scaleBuf + ((size_t)i * 32 + bn_t) * 16);
    float m[8], s[8];
#pragma unroll
    for (int k = 0; k < 8; ++k) { float2 p = sp[k]; m[k] = p.x; s[k] = p.y; }
    float M = m[0];
#pragma unroll
    for (int k = 1; k < 8; ++k) M = fmaxf(M, m[k]);
    float S = 0.0f;
#pragma unroll
    for (int k = 0; k < 8; ++k) S += s[k] * __expf(m[k] - M);
    sc_l[bn_t * 8 + c_t] = (S > 0.0f) ? (__expf(m[c_t] - M) / S) : 0.0f;
  }
  int bn0 = (tid & 7) << 2;                  // 4 consecutive bn per lane
  int jg = tid >> 3;                         // 0..31
  size_t ob = (size_t)i * 65536;
  // ---- zeros first: j in [0,i) and [i+1024,2048) — overlaps staging latency ----
  f32x4 z = {0.0f, 0.0f, 0.0f, 0.0f};
#pragma unroll
  for (int iter = 0; iter < 8; ++iter) {
    int z0 = 4 * jg + 128 * iter;
#pragma unroll
    for (int jj = 0; jj < 4; ++jj) {
      int zz = z0 + jj;
      int j = (zz < i) ? zz : zz + 1024;
      *(f32x4*)(out + ob + (size_t)j * 32 + bn0) = z;
    }
  }
  __syncthreads();
  float scv[4][8];
#pragma unroll
  for (int e = 0; e < 4; ++e)
#pragma unroll
    for (int cc = 0; cc < 8; ++cc) scv[e][cc] = sc_l[(bn0 + e) * 8 + cc];
  // ---- band: j = i + dd, dd in [0,1024) (P[dd<ddlo]==0 by construction) ----
#pragma unroll
  for (int iter = 0; iter < 8; ++iter) {
    int dd0 = 4 * jg + 128 * iter;           // 4-aligned; chunk cc == iter
    int u = dd0 >> 3, half = (dd0 >> 2) & 1;
    bf16x4 be[4];
#pragma unroll
    for (int e = 0; e < 4; ++e) {
      int bn = bn0 + e;
      int swu = u ^ ((bn >> 1) & 7);
      be[e] = *(const bf16x4*)((const char*)ld + bn * 2048 + (swu << 4) + half * 8);
    }
#pragma unroll
    for (int jj = 0; jj < 4; ++jj) {
      int j = i + dd0 + jj;
      f32x4 v;
#pragma unroll
      for (int e = 0; e < 4; ++e) v[e] = (float)be[e][jj] * scv[e][iter];
      *(f32x4*)(out + ob + (size_t)j * 32 + bn0) = v;
    }
  }
}

extern "C" void kernel_launch(void* const* d_in, const int* in_sizes, int n_in,
                              void* d_out, int out_size, void* d_ws, size_t ws_size,
                              hipStream_t stream) {
  const float* h   = (const float*)d_in[0];
  const float* m   = (const float*)d_in[1];
  const float* qw  = (const float*)d_in[2];
  const float* kw  = (const float*)d_in[3];
  const float* rw  = (const float*)d_in[4];
  const float* kb  = (const float*)d_in[5];
  const float* rb  = (const float*)d_in[6];
  const float* lns = (const float*)d_in[7];
  const float* lnb = (const float*)d_in[8];
  const void*  rst = d_in[9];
  const void* orst = d_in[10];
  float* out = (float*)d_out;
  char* ws = (char*)d_ws;

  int* jmin   = (int*)ws;                               // in first 64 KB slot
  bf16* catln = (bf16*)(ws + 65536);                    // 16 MB
  bf16* qwb   = catln + (size_t)8192 * 1024;            // 2 MB
  bf16* kwb   = qwb + (size_t)1024 * 1024;              // 2 MB
  bf16* rwb   = kwb + (size_t)1024 * 1024;              // 2 MB
  bf16* pe    = rwb + (size_t)1024 * 1024;              // 4 MB
  bf16* qkb   = pe + (size_t)2048 * 1024;               // [bn][1024][128] 8 MB
  bf16* qrb   = qkb + (size_t)4096 * 1024;              // 8 MB
  bf16* kk    = qrb + (size_t)4096 * 1024;              // [bn][2048][128] 16 MB
  bf16* rr    = kk + (size_t)8192 * 1024;               // [n][2048][128] 4 MB
  bf16* P     = rr + (size_t)2048 * 1024;               // [32][1024][1024] 64 MB
  float* scaleBuf = (float*)(P + (size_t)33554432);     // [1024][32][8][2] f32 = 2 MB
  size_t need_fast = (size_t)((char*)(scaleBuf + 524288) - ws);
  bool fast = ws_size >= need_fast;

  pre_kernel<<<28673, 256, 0, stream>>>(h, m, lns, lnb, catln, qw, kw, rw, qwb, kwb, rwb,
                                        pe, rst, orst, jmin);
  gemm_all<<<896, 256, 0, stream>>>(catln, pe, qwb, kwb, rwb, kb, rb, qkb, qrb, kk, rr);
  if (fast) {
    score2_kernel<<<1024, 256, 0, stream>>>(qkb, qrb, kk, rr, jmin, P, scaleBuf);
    scatter_kernel<<<1024, 256, 0, stream>>>(P, scaleBuf, out);
  } else {
    score_full<<<2048, 256, 0, stream>>>(qkb, qrb, kk, rr, jmin, out);
  }
}

// Round 17
// 211.153 us; speedup vs baseline: 1.0257x; 1.0257x over previous
//
#include <hip/hip_runtime.h>
#include <hip/hip_bf16.h>
#include <stdint.h>

// Transformer-XL attention prob: T=1024 B=4 D=1024 NH=8 DH=128 MEM=1024 TM=2048
typedef __bf16 bf16;
typedef __bf16 bf16x4 __attribute__((ext_vector_type(4)));
typedef __bf16 bf16x8 __attribute__((ext_vector_type(8)));
typedef float f32x4 __attribute__((ext_vector_type(4)));

__device__ __forceinline__ void gload_lds16(const void* g, void* l) {
  __builtin_amdgcn_global_load_lds((const __attribute__((address_space(1))) void*)g,
                                   (__attribute__((address_space(3))) void*)l, 16, 0, 0);
}

// ---------------- fused pre: ln (blocks 0..8191) + prep (8192..28671) + setup (28672) --
__global__ __launch_bounds__(256) void pre_kernel(const float* __restrict__ h, const float* __restrict__ mm,
                                                  const float* __restrict__ sc, const float* __restrict__ bi,
                                                  bf16* __restrict__ catln, const float* __restrict__ qw,
                                                  const float* __restrict__ kw, const float* __restrict__ rw,
                                                  bf16* __restrict__ qwb, bf16* __restrict__ kwb,
                                                  bf16* __restrict__ rwb, bf16* __restrict__ pe,
                                                  const void* __restrict__ rst, const void* __restrict__ orst,
                                                  int* __restrict__ jmin) {
  int bx = blockIdx.x;
  int tid = threadIdx.x;
  if (bx < 8192) {
    // ---- LayerNorm of concat(m,h) -> bf16 [TM*B][1024] ----
    int row = bx;
    const float* src = (row < 4096) ? (mm + (size_t)row * 1024) : (h + (size_t)(row - 4096) * 1024);
    float4 v = ((const float4*)src)[tid];
    float s1 = v.x + v.y + v.z + v.w;
    float s2 = v.x * v.x + v.y * v.y + v.z * v.z + v.w * v.w;
    int lane = tid & 63, w = tid >> 6;
    for (int o = 32; o; o >>= 1) { s1 += __shfl_down(s1, o); s2 += __shfl_down(s2, o); }
    __shared__ float red[8];
    if (lane == 0) { red[w] = s1; red[w + 4] = s2; }
    __syncthreads();
    float S1 = red[0] + red[1] + red[2] + red[3];
    float S2 = red[4] + red[5] + red[6] + red[7];
    float mean = S1 * (1.0f / 1024.0f);
    float var = S2 * (1.0f / 1024.0f) - mean * mean;
    float rstd = rsqrtf(var + 1e-5f);
    bf16x4 o;
#pragma unroll
    for (int c = 0; c < 4; ++c) {
      float x = (c == 0) ? v.x : (c == 1) ? v.y : (c == 2) ? v.z : v.w;
      o[c] = (bf16)((x - mean) * rstd * sc[tid * 4 + c] + bi[tid * 4 + c]);
    }
    *(bf16x4*)(catln + (size_t)row * 1024 + tid * 4) = o;
  } else if (bx < 28672) {
    // ---- weights->bf16 + positional encoding ----
    size_t id = (size_t)(bx - 8192) * 256 + tid;
    if (id < 3145728) {
      const float* s = id < 1048576 ? qw : (id < 2097152 ? kw : rw);
      bf16* d = id < 1048576 ? qwb : (id < 2097152 ? kwb : rwb);
      size_t o = id & 1048575;
      d[o] = (bf16)s[o];
    } else {
      size_t p = id - 3145728;                 // < 2097152
      int jj = (int)(p >> 10), dcol = (int)(p & 1023);
      float pos = (float)(2047 - jj);
      int fi = dcol < 512 ? dcol : dcol - 512;
      float f = exp2f(-0.01953125f * (float)fi);   // 1024^(-fi/512)
      float rev = pos * f;                          // revolutions
      rev -= floorf(rev);
      float ang = 6.283185307179586f * rev;
      pe[p] = (bf16)(dcol < 512 ? __sinf(ang) : __cosf(ang));
    }
  } else {
    // ---- setup: detect reset dtype, compute j_min per (i,b) ----
    __shared__ int sflag;
    if (tid == 0) sflag = 0;
    __syncthreads();
    int local = 0;
    for (int idx = tid; idx < 1024; idx += 256) {
      unsigned v1 = ((const unsigned*)rst)[idx];
      unsigned v2 = ((const unsigned*)orst)[idx];
      unsigned vv[2] = {v1, v2};
      for (int t = 0; t < 2; ++t) {
        unsigned v = vv[t];
        if (v == 0x3F800000u) local |= 1;
        else if (v > 1u) local |= 2;
      }
    }
    if (local) atomicOr(&sflag, local);
    __syncthreads();
    int mode = (sflag & 2) ? 2 : ((sflag & 1) ? 1 : 0);
    int lane = tid & 63, w = tid >> 6;
    if (w < 4) {
      int b = w;
      int rv[32];
      int lmax = -1;
#pragma unroll
      for (int u = 0; u < 32; ++u) {
        int s = lane * 32 + u;
        int idx = (s < 1024) ? s * 4 + b : (s - 1024) * 4 + b;
        const void* p = (s < 1024) ? orst : rst;
        int x;
        if (mode == 2)      x = ((const unsigned char*)p)[idx] != 0;
        else if (mode == 1) x = ((const float*)p)[idx] != 0.0f;
        else                x = ((const int*)p)[idx] != 0;
        rv[u] = x;
        if (x) lmax = s;
      }
      int inc = lmax;
      for (int o = 1; o < 64; o <<= 1) {
        int oth = __shfl_up(inc, o);
        if (lane >= o && oth > inc) inc = oth;
      }
      int cur = __shfl_up(inc, 1);
      if (lane == 0) cur = -1;
#pragma unroll
      for (int u = 0; u < 32; ++u) {
        int s = lane * 32 + u;
        if (rv[u]) cur = s;
        if (s >= 1024) jmin[(s - 1024) * 4 + b] = (cur > 0) ? cur : 0;
      }
    }
  }
}

// ---------------- fused GEMM: C = A(MxK) * W(NxK)^T, K=N=1024 -------------------------
__device__ __forceinline__ size_t out_index(int mode, int row, int col) {
  int n = col >> 7, dh = col & 127;
  if (mode <= 0) { int i = row >> 2, b = row & 3; return ((size_t)(b * 8 + n) * 1024 + i) * 128 + dh; }
  if (mode == 1) { int s = row >> 2, b = row & 3; return ((size_t)(b * 8 + n) * 2048 + s) * 128 + dh; }
  return ((size_t)n * 2048 + row) * 128 + dh;
}

__global__ __launch_bounds__(256) void gemm_all(const bf16* __restrict__ catln, const bf16* __restrict__ pe,
                                                const bf16* __restrict__ qwb, const bf16* __restrict__ kwb,
                                                const bf16* __restrict__ rwb, const float* __restrict__ kbias,
                                                const float* __restrict__ rbias, bf16* __restrict__ qkb,
                                                bf16* __restrict__ qrb, bf16* __restrict__ kkv,
                                                bf16* __restrict__ rrv) {
  __shared__ alignas(16) char lA[8192];
  __shared__ alignas(16) char lB[8192];
  const int K = 1024;
  int by = blockIdx.y;
  const bf16* A; const bf16* W; int mode; int brow;
  if (by < 32)      { mode = 0; A = catln + (size_t)4096 * 1024; W = qwb; brow = by << 7; }
  else if (by < 96) { mode = 1; A = catln;                        W = kwb; brow = (by - 32) << 7; }
  else              { mode = 2; A = pe;                           W = rwb; brow = (by - 96) << 7; }
  int tid = threadIdx.x;
  int lane = tid & 63, w = tid >> 6;
  int bcol = blockIdx.x << 7;
  int wr = w >> 1, wc = w & 1;
  f32x4 acc[4][4] = {};
  int r0 = tid >> 2;
  int c8 = (tid & 3) << 3;
  const bf16* gA0 = A + (size_t)(brow + r0) * K + c8;
  const bf16* gB0 = W + (size_t)(bcol + r0) * K + c8;
  char* lAw = lA + w * 1024;
  char* lBw = lB + w * 1024;
  for (int k0 = 0; k0 < K; k0 += 32) {
    if (k0) __syncthreads();
    gload_lds16(gA0 + k0, lAw);
    gload_lds16(gA0 + (size_t)64 * K + k0, lAw + 4096);
    gload_lds16(gB0 + k0, lBw);
    gload_lds16(gB0 + (size_t)64 * K + k0, lBw + 4096);
    __syncthreads();
    const char* pa = lA + (((wr << 6) + (lane & 15)) << 6) + ((lane >> 4) << 4);
    const char* pb = lB + (((wc << 6) + (lane & 15)) << 6) + ((lane >> 4) << 4);
    bf16x8 af[4], bfr[4];
#pragma unroll
    for (int x = 0; x < 4; ++x) {
      af[x] = *(const bf16x8*)(pa + (x << 10));
      bfr[x] = *(const bf16x8*)(pb + (x << 10));
    }
#pragma unroll
    for (int mi = 0; mi < 4; ++mi)
#pragma unroll
      for (int ni = 0; ni < 4; ++ni)
        acc[mi][ni] = __builtin_amdgcn_mfma_f32_16x16x32_bf16(af[mi], bfr[ni], acc[mi][ni], 0, 0, 0);
  }
  int rowb = brow + (wr << 6) + ((lane >> 4) << 2);
  int colb = bcol + (wc << 6) + (lane & 15);
#pragma unroll
  for (int mi = 0; mi < 4; ++mi)
#pragma unroll
    for (int ni = 0; ni < 4; ++ni) {
      int col = colb + (ni << 4);
      float bk = 0.0f, br = 0.0f;
      if (mode == 0) { bk = kbias[col]; br = rbias[col]; }
#pragma unroll
      for (int v = 0; v < 4; ++v) {
        int row = rowb + (mi << 4) + v;
        size_t idx = out_index(mode, row, col);
        if (mode == 0) {
          qkb[idx] = (bf16)(acc[mi][ni][v] + bk);
          qrb[idx] = (bf16)(acc[mi][ni][v] + br);
        } else if (mode == 1) {
          kkv[idx] = (bf16)acc[mi][ni][v];
        } else {
          rrv[idx] = (bf16)acc[mi][ni][v];
        }
      }
    }
}

// ---------------- score v7b: v7 structure; P unit-swizzle = (bn>>1)&7 ----------------
__global__ __launch_bounds__(256, 2) void score2_kernel(const bf16* __restrict__ qk, const bf16* __restrict__ qr,
                                                        const bf16* __restrict__ kk, const bf16* __restrict__ rr,
                                                        const int* __restrict__ jmin, bf16* __restrict__ P,
                                                        float* __restrict__ scaleBuf) {
  __shared__ float sl[64 * 128];                  // 32 KB, S1 scores [i][dd^xsw(i)]
  __shared__ alignas(16) bf16 stg[2][64 * 128];   // 2 x 16 KB pair buffers
  __shared__ int jl_s[64];
  int tid = threadIdx.x, lane = tid & 63;
  int w = (tid >> 6) & 3;
  int bid0 = blockIdx.x;
  int bid = ((bid0 & 7) << 7) | (bid0 >> 3);   // XCD grouping (1024 = 8*128, bijective)
  int bn = bid >> 5;
  int it = (bid >> 1) & 15;
  int hh = bid & 1;                             // dd-half: chunks 4hh..4hh+3
  int i0 = it << 6;
  int b = bn >> 3, n = bn & 7;
  int r15 = lane & 15, kc = lane >> 4;
  int il0 = w << 4;
  int g4 = kc << 2;
  const float scale = 0.08838834764831845f;    // 1/sqrt(128)
  int psw = (bn >> 1) & 7;                     // P unit swizzle (matches scatter)

  if (tid < 64) jl_s[tid] = jmin[(i0 + tid) * 4 + b];

  bf16x8 aK[4], aR[4];
  {
    const bf16* qkrow = qk + ((size_t)bn * 1024 + i0 + il0 + r15) * 128 + kc * 8;
    const bf16* qrrow = qr + ((size_t)bn * 1024 + i0 + il0 + r15) * 128 + kc * 8;
#pragma unroll
    for (int ks = 0; ks < 4; ++ks) {
      aK[ks] = *(const bf16x8*)(qkrow + ks * 32);
      aR[ks] = *(const bf16x8*)(qrrow + ks * 32);
    }
  }

  int su1 = tid, su2 = tid + 256;
  int srow1 = su1 >> 4, scol1 = (su1 & 15) ^ (srow1 & 7);
  int srow2 = su2 >> 4, scol2 = (su2 & 15) ^ (srow2 & 7);
  size_t do1 = (size_t)(su1 & ~63) * 16;
  size_t do2 = (size_t)(su2 & ~63) * 16;
  const bf16* rbase = rr + (size_t)n * 2048 * 128;
  const bf16* kbase = kk + (size_t)bn * 2048 * 128;

  auto issue_pair = [&](int pg) {
    if (pg >= 20) return;
    char* bufb = (char*)stg + (size_t)(pg & 1) * 16384;
#pragma unroll
    for (int k = 0; k < 2; ++k) {
      int ti = pg * 2 + k;
      int ci = ti / 10, si = ti - ci * 10;
      int gc = (hh << 2) + ci;
      const bf16* base = (si < 4) ? rbase : kbase;
      int row0 = (si < 4) ? (1023 + (gc << 7) + (si << 5)) : (i0 + (gc << 7) + ((si - 4) << 5));
      char* db = bufb + (size_t)k * 8192;
      gload_lds16(base + (size_t)(row0 + srow1) * 128 + scol1 * 8, db + do1);
      gload_lds16(base + (size_t)(row0 + srow2) * 128 + scol2 * 8, db + do2);
    }
  };

  int xsw = (((il0 >> 2) + kc) & 7) << 4;      // row-group swizzle (uniform over v)
  f32x4 s2r[8];

  issue_pair(0);
  for (int cl = 0; cl < 4; ++cl) {
    int gc = (hh << 2) + cl;
    int c128 = gc << 7;
#pragma unroll
    for (int q = 0; q < 5; ++q) {
      int g = cl * 5 + q;
      __syncthreads();                         // drains vmcnt -> pair g data visible
      issue_pair(g + 1);                       // overwrites pair g-1's buffer (safe)
      const char* pb = (const char*)stg + (size_t)(g & 1) * 16384;
      __builtin_amdgcn_s_setprio(1);
      if (q < 2) {
#pragma unroll
        for (int sc = 0; sc < 4; ++sc) {
          const char* sb = pb + (sc >> 1) * 8192;
          int fr = ((sc & 1) << 4) + r15;
          f32x4 acc = {};
#pragma unroll
          for (int ks = 0; ks < 4; ++ks) {
            int lcol = (ks << 2) + kc;
            bf16x8 bf = *(const bf16x8*)(sb + fr * 256 + ((lcol ^ (fr & 7)) << 4));
            acc = __builtin_amdgcn_mfma_f32_16x16x32_bf16(aR[ks], bf, acc, 0, 0, 0);
          }
          s2r[q * 4 + sc] = acc;
        }
      } else {
#pragma unroll
        for (int sc = 0; sc < 4; ++sc) {
          int jl0 = ((q - 2) << 6) + (sc << 4);
          int doff = jl0 - il0;
          if (doff < -15 || doff > 142) continue;
          const char* sb = pb + (sc >> 1) * 8192;
          int fr = ((sc & 1) << 4) + r15;
          f32x4 acc = {};
#pragma unroll
          for (int ks = 0; ks < 4; ++ks) {
            int lcol = (ks << 2) + kc;
            bf16x8 bf = *(const bf16x8*)(sb + fr * 256 + ((lcol ^ (fr & 7)) << 4));
            acc = __builtin_amdgcn_mfma_f32_16x16x32_bf16(aK[ks], bf, acc, 0, 0, 0);
          }
          int dbase = jl0 + r15 - il0 - g4;   // ddl = jl - il
#pragma unroll
          for (int v = 0; v < 4; ++v) {
            int ddl = dbase - v;
            if ((unsigned)ddl < 128u) {
              sl[(il0 + g4 + v) * 128 + (ddl ^ xsw)] = acc[v];
            }
          }
        }
      }
      __builtin_amdgcn_s_setprio(0);
      if (q == 4) {
#pragma unroll
        for (int v = 0; v < 4; ++v) {
          int il = il0 + g4 + v;
          int ig = i0 + il;
          int jm = jl_s[il];
          int lo = (ig + 1 > jm) ? ig + 1 : jm;
          int ddlo = lo - ig;
          float vals[8];
          float mx = -3.0e38f;
#pragma unroll
          for (int u = 0; u < 8; ++u) {
            int ddc = (u << 4) + r15;              // chunk-local dd
            float x = (s2r[u][v] + sl[il * 128 + (ddc ^ xsw)]) * scale;
            x = fminf(fmaxf(x, -65000.0f), 65000.0f);
            float xm = ((c128 + ddc) >= ddlo) ? x : -3.0e38f;
            vals[u] = xm;
            mx = fmaxf(mx, xm);
          }
          for (int o = 8; o; o >>= 1) mx = fmaxf(mx, __shfl_xor(mx, o));
          float sum = 0.0f;
#pragma unroll
          for (int u = 0; u < 8; ++u) {
            float e = (vals[u] > -1.0e38f) ? __expf(vals[u] - mx) : 0.0f;
            vals[u] = e;
            sum += e;
          }
          for (int o = 8; o; o >>= 1) sum += __shfl_xor(sum, o);
          size_t pbase = ((size_t)bn * 1024 + ig) * 1024;
#pragma unroll
          for (int u = 0; u < 8; ++u) {
            int dd = c128 + (u << 4) + r15;
            P[pbase + (((dd >> 3) ^ psw) << 3) + (dd & 7)] = (bf16)vals[u];
          }
          if (r15 == 0) {
            float2 ms = make_float2(mx, sum);
            *(float2*)(scaleBuf + (((size_t)ig * 32 + bn) * 8 + gc) * 2) = ms;
          }
        }
      }
    }
  }
}

// ---------------- fallback: full-LDS score writing normalized out directly -----------
__global__ __launch_bounds__(256) void score_full(const bf16* __restrict__ qk, const bf16* __restrict__ qr,
                                                  const bf16* __restrict__ kk, const bf16* __restrict__ rr,
                                                  const int* __restrict__ jmin, float* __restrict__ out) {
  __shared__ float sl[16 * 1024];
  int tid = threadIdx.x, lane = tid & 63, w = tid >> 6;
  int bid = blockIdx.x;
  int i0 = (bid & 63) << 4;
  int bn = bid >> 6;
  int b = bn >> 3, n = bn & 7;
  int r15 = lane & 15, kc = lane >> 4;
  bf16x8 aq[4], ar[4];
  {
    const bf16* qkrow = qk + ((size_t)bn * 1024 + i0 + r15) * 128 + kc * 8;
    const bf16* qrrow = qr + ((size_t)bn * 1024 + i0 + r15) * 128 + kc * 8;
#pragma unroll
    for (int f = 0; f < 4; ++f) {
      aq[f] = *(const bf16x8*)(qkrow + f * 32);
      ar[f] = *(const bf16x8*)(qrrow + f * 32);
    }
  }
  for (int t = w; t < 64; t += 4) {
    int dd0 = t << 4;
    const bf16* rrow = rr + ((size_t)n * 2048 + 1023 + dd0 + r15) * 128 + kc * 8;
    f32x4 acc = {};
#pragma unroll
    for (int f = 0; f < 4; ++f)
      acc = __builtin_amdgcn_mfma_f32_16x16x32_bf16(ar[f], *(const bf16x8*)(rrow + f * 32), acc, 0, 0, 0);
    int dd = dd0 + r15;
#pragma unroll
    for (int v = 0; v < 4; ++v) sl[(kc * 4 + v) * 1024 + dd] = acc[v];
  }
  __syncthreads();
  for (int t = w; t < 65; t += 4) {
    int j0 = i0 + (t << 4);
    const bf16* krow = kk + ((size_t)bn * 2048 + j0 + r15) * 128 + kc * 8;
    f32x4 acc = {};
#pragma unroll
    for (int f = 0; f < 4; ++f)
      acc = __builtin_amdgcn_mfma_f32_16x16x32_bf16(aq[f], *(const bf16x8*)(krow + f * 32), acc, 0, 0, 0);
    int jc = (t << 4) + r15;
#pragma unroll
    for (int v = 0; v < 4; ++v) {
      int ii = kc * 4 + v;
      int dd = jc - ii;
      if (dd >= 1 && dd <= 1023) sl[ii * 1024 + dd] += acc[v];
    }
  }
  __syncthreads();
  const float scale = 0.08838834764831845f;
  for (int ii = w; ii < 16; ii += 4) {
    int i = i0 + ii;
    int jm = jmin[i * 4 + b];
    int lo = (i + 1 > jm) ? i + 1 : jm;
    int ddlo = lo - i;
    size_t ob = (size_t)i * 65536 + bn;
    if (ddlo > 1023) {
      for (int j = lane; j < 2048; j += 64) out[ob + (size_t)j * 32] = 0.0f;
      continue;
    }
    float vals[16];
    float mx = -3.0e38f;
#pragma unroll
    for (int c = 0; c < 16; ++c) {
      int dd = (c << 6) + lane;
      float x = sl[ii * 1024 + dd] * scale;
      x = fminf(fmaxf(x, -65000.0f), 65000.0f);
      float xm = (dd >= ddlo) ? x : -3.0e38f;
      vals[c] = xm;
      mx = fmaxf(mx, xm);
    }
    for (int o = 32; o; o >>= 1) mx = fmaxf(mx, __shfl_xor(mx, o));
    float sum = 0.0f;
#pragma unroll
    for (int c = 0; c < 16; ++c) {
      float e = (vals[c] > -1.0e38f) ? __expf(vals[c] - mx) : 0.0f;
      vals[c] = e;
      sum += e;
    }
    for (int o = 32; o; o >>= 1) sum += __shfl_xor(sum, o);
    float inv = 1.0f / sum;
    for (int j = lane; j < 2048; j += 64) {
      int dd = j - i;
      float pv = 0.0f;
      if (dd >= ddlo && dd <= 1023) {
        float x = sl[ii * 1024 + dd] * scale;
        x = fminf(fmaxf(x, -65000.0f), 65000.0f);
        pv = __expf(x - mx) * inv;
      }
      out[ob + (size_t)j * 32] = pv;
    }
  }
}

// ---------------- scatter v3: zero-writes overlap the P->LDS staging -----------------
__global__ __launch_bounds__(256) void scatter_kernel(const bf16* __restrict__ P,
                                                      const float* __restrict__ scaleBuf,
                                                      float* __restrict__ out) {
  __shared__ alignas(16) bf16 ld[32 * 1024];  // 64 KB
  __shared__ float sc_l[32 * 8];
  int i = blockIdx.x;
  int tid = threadIdx.x;
#pragma unroll
  for (int it = 0; it < 16; ++it) {
    int c = it * 256 + tid;                 // 16B-units; bn uniform per wave
    int bn = c >> 7, u = c & 127;
    const bf16* src = P + ((size_t)bn * 1024 + i) * 1024 + u * 8;
    gload_lds16(src, (char*)ld + (size_t)(it * 256 + (tid & ~63)) * 16);
  }
  {
    int bn_t = tid >> 3, c_t = tid & 7;
    const float2* sp = (const float2*)(scaleBuf + ((size_t)i * 32 + bn_t) * 16);
    float m[8], s[8];
#pragma unroll
    for (int k = 0; k < 8; ++k) { float2 p = sp[k]; m[k] = p.x; s[k] = p.y; }
    float M = m[0];
#pragma unroll
    for (int k = 1; k < 8; ++k) M = fmaxf(M, m[k]);
    float S = 0.0f;
#pragma unroll
    for (int k = 0; k < 8; ++k) S += s[k] * __expf(m[k] - M);
    sc_l[bn_t * 8 + c_t] = (S > 0.0f) ? (__expf(m[c_t] - M) / S) : 0.0f;
  }
  int bn0 = (tid & 7) << 2;                  // 4 consecutive bn per lane
  int jg = tid >> 3;                         // 0..31
  size_t ob = (size_t)i * 65536;
  // ---- zeros first: j in [0,i) and [i+1024,2048) — overlaps staging latency ----
  f32x4 z = {0.0f, 0.0f, 0.0f, 0.0f};
#pragma unroll
  for (int iter = 0; iter < 8; ++iter) {
    int z0 = 4 * jg + 128 * iter;
#pragma unroll
    for (int jj = 0; jj < 4; ++jj) {
      int zz = z0 + jj;
      int j = (zz < i) ? zz : zz + 1024;
      *(f32x4*)(out + ob + (size_t)j * 32 + bn0) = z;
    }
  }
  __syncthreads();
  float scv[4][8];
#pragma unroll
  for (int e = 0; e < 4; ++e)
#pragma unroll
    for (int cc = 0; cc < 8; ++cc) scv[e][cc] = sc_l[(bn0 + e) * 8 + cc];
  // ---- band: j = i + dd, dd in [0,1024) (P[dd<ddlo]==0 by construction) ----
#pragma unroll
  for (int iter = 0; iter < 8; ++iter) {
    int dd0 = 4 * jg + 128 * iter;           // 4-aligned; chunk cc == iter
    int u = dd0 >> 3, half = (dd0 >> 2) & 1;
    bf16x4 be[4];
#pragma unroll
    for (int e = 0; e < 4; ++e) {
      int bn = bn0 + e;
      int swu = u ^ ((bn >> 1) & 7);
      be[e] = *(const bf16x4*)((const char*)ld + bn * 2048 + (swu << 4) + half * 8);
    }
#pragma unroll
    for (int jj = 0; jj < 4; ++jj) {
      int j = i + dd0 + jj;
      f32x4 v;
#pragma unroll
      for (int e = 0; e < 4; ++e) v[e] = (float)be[e][jj] * scv[e][iter];
      *(f32x4*)(out + ob + (size_t)j * 32 + bn0) = v;
    }
  }
}

extern "C" void kernel_launch(void* const* d_in, const int* in_sizes, int n_in,
                              void* d_out, int out_size, void* d_ws, size_t ws_size,
                              hipStream_t stream) {
  const float* h   = (const float*)d_in[0];
  const float* m   = (const float*)d_in[1];
  const float* qw  = (const float*)d_in[2];
  const float* kw  = (const float*)d_in[3];
  const float* rw  = (const float*)d_in[4];
  const float* kb  = (const float*)d_in[5];
  const float* rb  = (const float*)d_in[6];
  const float* lns = (const float*)d_in[7];
  const float* lnb = (const float*)d_in[8];
  const void*  rst = d_in[9];
  const void* orst = d_in[10];
  float* out = (float*)d_out;
  char* ws = (char*)d_ws;

  int* jmin   = (int*)ws;                               // in first 64 KB slot
  bf16* catln = (bf16*)(ws + 65536);                    // 16 MB
  bf16* qwb   = catln + (size_t)8192 * 1024;            // 2 MB
  bf16* kwb   = qwb + (size_t)1024 * 1024;              // 2 MB
  bf16* rwb   = kwb + (size_t)1024 * 1024;              // 2 MB
  bf16* pe    = rwb + (size_t)1024 * 1024;              // 4 MB
  bf16* qkb   = pe + (size_t)2048 * 1024;               // [bn][1024][128] 8 MB
  bf16* qrb   = qkb + (size_t)4096 * 1024;              // 8 MB
  bf16* kk    = qrb + (size_t)4096 * 1024;              // [bn][2048][128] 16 MB
  bf16* rr    = kk + (size_t)8192 * 1024;               // [n][2048][128] 4 MB
  bf16* P     = rr + (size_t)2048 * 1024;               // [32][1024][1024] 64 MB
  float* scaleBuf = (float*)(P + (size_t)33554432);     // [1024][32][8][2] f32 = 2 MB
  size_t need_fast = (size_t)((char*)(scaleBuf + 524288) - ws);
  bool fast = ws_size >= need_fast;

  pre_kernel<<<28673, 256, 0, stream>>>(h, m, lns, lnb, catln, qw, kw, rw, qwb, kwb, rwb,
                                        pe, rst, orst, jmin);
  gemm_all<<<dim3(8, 112), 256, 0, stream>>>(catln, pe, qwb, kwb, rwb, kb, rb, qkb, qrb, kk, rr);
  if (fast) {
    score2_kernel<<<1024, 256, 0, stream>>>(qkb, qrb, kk, rr, jmin, P, scaleBuf);
    scatter_kernel<<<1024, 256, 0, stream>>>(P, scaleBuf, out);
  } else {
    score_full<<<2048, 256, 0, stream>>>(qkb, qrb, kk, rr, jmin, out);
  }
}